// Round 1
// baseline (1779.151 us; speedup 1.0000x reference)
//
#include <hip/hip_runtime.h>
#include <math.h>

#define MORD 862

__global__ __launch_bounds__(256) void deg_kernel(const int* __restrict__ dst, int* __restrict__ deg, int E) {
  int e = blockIdx.x * blockDim.x + threadIdx.x;
  if (e < E) atomicAdd(&deg[dst[e]], 1);
}

template <int C>
__global__ __launch_bounds__(256) void scatter_kernel(const float* __restrict__ x, const int* __restrict__ src,
                                                      const int* __restrict__ dst, float* __restrict__ h, int E) {
  long long tid = (long long)blockIdx.x * blockDim.x + threadIdx.x;
  if (tid >= (long long)E * C) return;
  int e = (int)(tid / C);
  int c = (int)(tid % C);
  atomicAdd(&h[(long long)dst[e] * C + c], x[(long long)src[e] * C + c]);
}

// out[n][o] = bl[d][o] + sum_i Wl[d][o][i]*hagg[n][i] + Wr[d][o][i]*x[n][i]
template <int CIN, bool RELU>
__global__ __launch_bounds__(256) void transform_kernel(const float* __restrict__ hagg, const float* __restrict__ xin,
                                                        const int* __restrict__ deg,
                                                        const float* __restrict__ Wl, const float* __restrict__ bl,
                                                        const float* __restrict__ Wr,
                                                        float* __restrict__ out, int N) {
  __shared__ float sh[8][CIN];
  __shared__ float sx[8][CIN];
  int n0 = blockIdx.x * 8;
  for (int i = threadIdx.x; i < 8 * CIN; i += 256) {
    int nn = i / CIN, cc = i % CIN;
    long long n = (long long)n0 + nn;
    sh[nn][cc] = hagg[n * CIN + cc];
    sx[nn][cc] = xin[n * CIN + cc];
  }
  __syncthreads();
  int ln = threadIdx.x >> 5, o = threadIdx.x & 31;
  int n = n0 + ln;
  if (n >= N) return;
  int d = min(deg[n], 10);
  const float* wl = Wl + ((long long)d * 32 + o) * CIN;
  const float* wr = Wr + ((long long)d * 32 + o) * CIN;
  float acc = bl[d * 32 + o];
#pragma unroll
  for (int i = 0; i < CIN; i++) acc = fmaf(wl[i], sh[ln][i], fmaf(wr[i], sx[ln][i], acc));
  if (RELU) acc = fmaxf(acc, 0.f);
  out[(long long)n * 32 + o] = acc;
}

__global__ __launch_bounds__(256) void pool_kernel(const float* __restrict__ h, const int* __restrict__ batch,
                                                   float* __restrict__ pooled, float* __restrict__ cnt, int N) {
  long long tid = (long long)blockIdx.x * blockDim.x + threadIdx.x;
  if (tid >= (long long)N * 32) return;
  int n = (int)(tid >> 5), c = (int)(tid & 31);
  int b = batch[n];
  atomicAdd(&pooled[(long long)b * 32 + c], h[tid]);
  if (c == 0) atomicAdd(&cnt[b], 1.f);
}

// C = A[M,K] (optional per-col scale/shift) @ Bw[N,K]^T + bias, optional relu
template <bool RELU>
__global__ __launch_bounds__(256) void gemm_bias(const float* __restrict__ A, const float* __restrict__ Bw,
                                                 const float* __restrict__ bias,
                                                 const float* __restrict__ scA, const float* __restrict__ shA,
                                                 float* __restrict__ C, int M, int Nn, int K) {
  const int BM = 64, BN = 64, BK = 16;
  __shared__ float As[BK][BM + 1];
  __shared__ float Bs[BK][BN + 1];
  int bm = blockIdx.y * BM, bn = blockIdx.x * BN;
  int tid = threadIdx.x;
  int tr = tid / 16, tc = tid % 16;
  float acc[4][4] = {};
  for (int k0 = 0; k0 < K; k0 += BK) {
    for (int i = tid; i < BM * BK; i += 256) {
      int m = i / BK, k = i % BK;
      float v = 0.f;
      if (k0 + k < K) {
        v = A[(size_t)(bm + m) * K + k0 + k];
        if (scA) v = fmaf(v, scA[k0 + k], shA[k0 + k]);
      }
      As[k][m] = v;
    }
    for (int i = tid; i < BN * BK; i += 256) {
      int n = i / BK, k = i % BK;
      float v = 0.f;
      if (k0 + k < K) v = Bw[(size_t)(bn + n) * K + k0 + k];
      Bs[k][n] = v;
    }
    __syncthreads();
#pragma unroll
    for (int k = 0; k < BK; k++) {
      float a4[4], b4[4];
#pragma unroll
      for (int xx = 0; xx < 4; xx++) a4[xx] = As[k][tr * 4 + xx];
#pragma unroll
      for (int yy = 0; yy < 4; yy++) b4[yy] = Bs[k][tc * 4 + yy];
#pragma unroll
      for (int xx = 0; xx < 4; xx++)
#pragma unroll
        for (int yy = 0; yy < 4; yy++) acc[xx][yy] = fmaf(a4[xx], b4[yy], acc[xx][yy]);
    }
    __syncthreads();
  }
  for (int xx = 0; xx < 4; xx++) {
    int m = bm + tr * 4 + xx;
    for (int yy = 0; yy < 4; yy++) {
      int n = bn + tc * 4 + yy;
      float v = acc[xx][yy] + bias[n];
      if (RELU) v = fmaxf(v, 0.f);
      C[(size_t)m * Nn + n] = v;
    }
  }
}

// per-column sum & sumsq over X[M,C]; blockDim=256 (64 cols x 4 rows), grid (C/64, M/256)
__global__ __launch_bounds__(256) void colstats_kernel(const float* __restrict__ X, int M, int C,
                                                       float* __restrict__ sum, float* __restrict__ sumsq) {
  int cl = threadIdx.x & 63, rl = threadIdx.x >> 6;
  int c = blockIdx.x * 64 + cl;
  float s = 0.f, q = 0.f;
  int r0 = blockIdx.y * 256;
  int rend = min(r0 + 256, M);
  for (int r = r0 + rl; r < rend; r += 4) {
    float v = X[(size_t)r * C + c];
    s += v;
    q = fmaf(v, v, q);
  }
  __shared__ float ss[4][64];
  __shared__ float qq[4][64];
  ss[rl][cl] = s;
  qq[rl][cl] = q;
  __syncthreads();
  if (rl == 0) {
    s = ss[0][cl] + ss[1][cl] + ss[2][cl] + ss[3][cl];
    q = qq[0][cl] + qq[1][cl] + qq[2][cl] + qq[3][cl];
    atomicAdd(&sum[c], s);
    atomicAdd(&sumsq[c], q);
  }
}

__global__ __launch_bounds__(256) void bn_coef_kernel(const float* __restrict__ sum, const float* __restrict__ sumsq,
                                                      const float* __restrict__ g, const float* __restrict__ be,
                                                      float* __restrict__ a, float* __restrict__ b, int C, float invM) {
  int c = blockIdx.x * blockDim.x + threadIdx.x;
  if (c >= C) return;
  float mu = sum[c] * invM;
  float var = sumsq[c] * invM - mu * mu;
  float s = g[c] * rsqrtf(var + 1e-5f);
  a[c] = s;
  b[c] = be[c] - mu * s;
}

__global__ __launch_bounds__(256) void head_kernel(const float* __restrict__ pooled, const float* __restrict__ cnt,
                                                   const float* __restrict__ m3, const float* __restrict__ a3,
                                                   const float* __restrict__ b3, const float* __restrict__ Wout,
                                                   const float* __restrict__ bout, float* __restrict__ out, int B) {
  int b = blockIdx.x * blockDim.x + threadIdx.x;
  if (b >= B) return;
  float inv = 1.f / fmaxf(cnt[b], 1.f);
  float acc = bout[0];
#pragma unroll
  for (int j = 0; j < 32; j++) acc = fmaf(pooled[(size_t)b * 32 + j] * inv, Wout[j], acc);
#pragma unroll
  for (int j = 0; j < 64; j++) acc = fmaf(fmaf(m3[(size_t)b * 64 + j], a3[j], b3[j]), Wout[32 + j], acc);
  out[b] = 1.f / (1.f + expf(-acc));
}

extern "C" void kernel_launch(void* const* d_in, const int* in_sizes, int n_in,
                              void* d_out, int out_size, void* d_ws, size_t ws_size,
                              hipStream_t stream) {
  const float* x = (const float*)d_in[0];
  const int* eidx = (const int*)d_in[1];
  const int* batch = (const int*)d_in[2];
  const float* xmord = (const float*)d_in[3];
  const float* Wl1 = (const float*)d_in[4];
  const float* bl1 = (const float*)d_in[5];
  const float* Wr1 = (const float*)d_in[6];
  const float* Wl2 = (const float*)d_in[7];
  const float* bl2 = (const float*)d_in[8];
  const float* Wr2 = (const float*)d_in[9];
  const float* Wl3 = (const float*)d_in[10];
  const float* bl3 = (const float*)d_in[11];
  const float* Wr3 = (const float*)d_in[12];
  const float* Wf1 = (const float*)d_in[13];
  const float* bf1 = (const float*)d_in[14];
  const float* g1 = (const float*)d_in[15];
  const float* be1 = (const float*)d_in[16];
  const float* Wf2 = (const float*)d_in[17];
  const float* bf2 = (const float*)d_in[18];
  const float* g2 = (const float*)d_in[19];
  const float* be2 = (const float*)d_in[20];
  const float* Wf3 = (const float*)d_in[21];
  const float* bf3 = (const float*)d_in[22];
  const float* g3 = (const float*)d_in[23];
  const float* be3 = (const float*)d_in[24];
  const float* Wout = (const float*)d_in[25];
  const float* bout = (const float*)d_in[26];
  float* out = (float*)d_out;

  const int N = in_sizes[2];
  const int E = in_sizes[1] / 2;
  const int B = in_sizes[3] / MORD;
  const int* src = eidx;
  const int* dst = eidx + E;

  char* ws = (char*)d_ws;
  size_t off = 0;
  auto alloc = [&](size_t bytes) { size_t o = off; off += (bytes + 255) & ~(size_t)255; return o; };
  size_t oAGG = alloc((size_t)N * 32 * 4);
  size_t oA = alloc((size_t)N * 32 * 4);
  size_t oB = alloc((size_t)N * 32 * 4);
  size_t oDeg = alloc((size_t)N * 4);
  size_t oPool = alloc((size_t)B * 32 * 4);
  size_t oCnt = alloc((size_t)B * 4);
  size_t oStats = alloc(4096 * 4);
  (void)ws_size;

  float* AGG = (float*)(ws + oAGG);
  float* OA = (float*)(ws + oA);
  float* OB = (float*)(ws + oB);
  int* deg = (int*)(ws + oDeg);
  float* pooled = (float*)(ws + oPool);
  float* cnt = (float*)(ws + oCnt);
  float* st = (float*)(ws + oStats);
  float *s1 = st, *q1 = st + 512, *a1 = st + 1024, *h1 = st + 1536;
  float *s2 = st + 2048, *q2 = st + 2176, *a2 = st + 2304, *h2 = st + 2432;
  float *s3 = st + 2560, *q3 = st + 2624, *a3 = st + 2688, *h3 = st + 2752;
  // MLP buffers reuse graph buffers (stream-serialized, no overlap of live ranges)
  float* m1 = AGG;                      // [B,512] after transform3 done with AGG
  float* m2 = OB;                       // [B,128] after transform3 done with OB
  float* m3 = OB + (size_t)B * 128;     // [B,64]

  hipMemsetAsync(deg, 0, (size_t)N * 4, stream);
  hipMemsetAsync(AGG, 0, (size_t)N * 8 * 4, stream);
  hipMemsetAsync(pooled, 0, (size_t)B * 32 * 4, stream);
  hipMemsetAsync(cnt, 0, (size_t)B * 4, stream);
  hipMemsetAsync(st, 0, 4096 * 4, stream);

  deg_kernel<<<(E + 255) / 256, 256, 0, stream>>>(dst, deg, E);

  // layer 1 (Cin=8)
  scatter_kernel<8><<<(int)(((long long)E * 8 + 255) / 256), 256, 0, stream>>>(x, src, dst, AGG, E);
  transform_kernel<8, true><<<N / 8, 256, 0, stream>>>(AGG, x, deg, Wl1, bl1, Wr1, OA, N);

  // layer 2 (Cin=32)
  hipMemsetAsync(AGG, 0, (size_t)N * 32 * 4, stream);
  scatter_kernel<32><<<(int)(((long long)E * 32 + 255) / 256), 256, 0, stream>>>(OA, src, dst, AGG, E);
  transform_kernel<32, true><<<N / 8, 256, 0, stream>>>(AGG, OA, deg, Wl2, bl2, Wr2, OB, N);

  // layer 3 (Cin=32)
  hipMemsetAsync(AGG, 0, (size_t)N * 32 * 4, stream);
  scatter_kernel<32><<<(int)(((long long)E * 32 + 255) / 256), 256, 0, stream>>>(OB, src, dst, AGG, E);
  transform_kernel<32, false><<<N / 8, 256, 0, stream>>>(AGG, OB, deg, Wl3, bl3, Wr3, OA, N);

  pool_kernel<<<(int)(((long long)N * 32 + 255) / 256), 256, 0, stream>>>(OA, batch, pooled, cnt, N);

  // MLP head
  gemm_bias<true><<<dim3(512 / 64, B / 64), 256, 0, stream>>>(xmord, Wf1, bf1, nullptr, nullptr, m1, B, 512, MORD);
  colstats_kernel<<<dim3(512 / 64, B / 256), 256, 0, stream>>>(m1, B, 512, s1, q1);
  bn_coef_kernel<<<2, 256, 0, stream>>>(s1, q1, g1, be1, a1, h1, 512, 1.f / B);

  gemm_bias<true><<<dim3(128 / 64, B / 64), 256, 0, stream>>>(m1, Wf2, bf2, a1, h1, m2, B, 128, 512);
  colstats_kernel<<<dim3(128 / 64, B / 256), 256, 0, stream>>>(m2, B, 128, s2, q2);
  bn_coef_kernel<<<1, 256, 0, stream>>>(s2, q2, g2, be2, a2, h2, 128, 1.f / B);

  gemm_bias<true><<<dim3(64 / 64, B / 64), 256, 0, stream>>>(m2, Wf3, bf3, a2, h2, m3, B, 64, 128);
  colstats_kernel<<<dim3(1, B / 256), 256, 0, stream>>>(m3, B, 64, s3, q3);
  bn_coef_kernel<<<1, 256, 0, stream>>>(s3, q3, g3, be3, a3, h3, 64, 1.f / B);

  head_kernel<<<(B + 255) / 256, 256, 0, stream>>>(pooled, cnt, m3, a3, h3, Wout, bout, out, B);
}

// Round 2
// 1365.243 us; speedup vs baseline: 1.3032x; 1.3032x over previous
//
#include <hip/hip_runtime.h>
#include <hip/hip_bf16.h>
#include <math.h>

#define MORD 862

typedef short s16x8 __attribute__((ext_vector_type(8)));
typedef float f32x4 __attribute__((ext_vector_type(4)));

static __device__ __forceinline__ unsigned short f2bf(float v) {
  __hip_bfloat16 h = __float2bfloat16(v);
  return *(unsigned short*)&h;
}

__global__ __launch_bounds__(256) void deg_kernel(const int* __restrict__ dst, int* __restrict__ deg, int E) {
  int e = blockIdx.x * blockDim.x + threadIdx.x;
  if (e < E) atomicAdd(&deg[dst[e]], 1);
}

template <int C>
__global__ __launch_bounds__(256) void scatter_kernel(const float* __restrict__ x, const int* __restrict__ src,
                                                      const int* __restrict__ dst, float* __restrict__ h, int E) {
  long long tid = (long long)blockIdx.x * blockDim.x + threadIdx.x;
  if (tid >= (long long)E * C) return;
  int e = (int)(tid / C);
  int c = (int)(tid % C);
  atomicAdd(&h[(long long)dst[e] * C + c], x[(long long)src[e] * C + c]);
}

template <int CIN, bool RELU>
__global__ __launch_bounds__(256) void transform_kernel(const float* __restrict__ hagg, const float* __restrict__ xin,
                                                        const int* __restrict__ deg,
                                                        const float* __restrict__ Wl, const float* __restrict__ bl,
                                                        const float* __restrict__ Wr,
                                                        float* __restrict__ out, int N) {
  __shared__ float sh[8][CIN];
  __shared__ float sx[8][CIN];
  int n0 = blockIdx.x * 8;
  for (int i = threadIdx.x; i < 8 * CIN; i += 256) {
    int nn = i / CIN, cc = i % CIN;
    long long n = (long long)n0 + nn;
    sh[nn][cc] = hagg[n * CIN + cc];
    sx[nn][cc] = xin[n * CIN + cc];
  }
  __syncthreads();
  int ln = threadIdx.x >> 5, o = threadIdx.x & 31;
  int n = n0 + ln;
  if (n >= N) return;
  int d = min(deg[n], 10);
  const float* wl = Wl + ((long long)d * 32 + o) * CIN;
  const float* wr = Wr + ((long long)d * 32 + o) * CIN;
  float acc = bl[d * 32 + o];
#pragma unroll
  for (int i = 0; i < CIN; i++) acc = fmaf(wl[i], sh[ln][i], fmaf(wr[i], sx[ln][i], acc));
  if (RELU) acc = fmaxf(acc, 0.f);
  out[(long long)n * 32 + o] = acc;
}

__global__ __launch_bounds__(256) void pool_kernel(const float* __restrict__ h, const int* __restrict__ batch,
                                                   float* __restrict__ pooled, float* __restrict__ cnt, int N) {
  long long tid = (long long)blockIdx.x * blockDim.x + threadIdx.x;
  if (tid >= (long long)N * 32) return;
  int n = (int)(tid >> 5), c = (int)(tid & 31);
  int b = batch[n];
  atomicAdd(&pooled[(long long)b * 32 + c], h[tid]);
  if (c == 0) atomicAdd(&cnt[b], 1.f);
}

// fp32 -> bf16 with K padding to Kp (zeros in pad)
__global__ __launch_bounds__(256) void cvt_bf16_pad(const float* __restrict__ src, unsigned short* __restrict__ dst,
                                                    int rows, int K, int Kp) {
  int t = blockIdx.x * blockDim.x + threadIdx.x;
  int q = Kp / 4;
  if (t >= rows * q) return;
  int r = t / q, c4 = (t % q) * 4;
#pragma unroll
  for (int j = 0; j < 4; j++) {
    int k = c4 + j;
    float v = (k < K) ? src[(size_t)r * K + k] : 0.f;
    dst[(size_t)r * Kp + k] = f2bf(v);
  }
}

// W2'[n][k] = bf16(W2[n][k]*a1[k]); b2'[n] = b2[n] + sum_k h1[k]*W2[n][k].  one wave per n.
__global__ __launch_bounds__(256) void prepW2_kernel(const float* __restrict__ W2, const float* __restrict__ b2,
                                                     const float* __restrict__ a1, const float* __restrict__ h1,
                                                     unsigned short* __restrict__ W2p, float* __restrict__ b2p,
                                                     int Nn, int K) {
  int wid = threadIdx.x >> 6, lane = threadIdx.x & 63;
  int n = blockIdx.x * 4 + wid;
  if (n >= Nn) return;
  float part = 0.f;
  for (int k = lane; k < K; k += 64) {
    float w = W2[(size_t)n * K + k];
    W2p[(size_t)n * K + k] = f2bf(w * a1[k]);
    part = fmaf(w, h1[k], part);
  }
#pragma unroll
  for (int off = 32; off > 0; off >>= 1) part += __shfl_down(part, off, 64);
  if (lane == 0) b2p[n] = b2[n] + part;
}

// bf16 MFMA GEMM: C[M,Nn] = relu(A[M,Kp] @ Bw[Nn,Kp]^T + bias). 128x128 tile, BK=64.
template <int OUTBF16>
__global__ __launch_bounds__(256) void gemm_mfma(const unsigned short* __restrict__ A,
                                                 const unsigned short* __restrict__ Bw,
                                                 const float* __restrict__ bias,
                                                 void* __restrict__ Cout, int M, int Nn, int Kp) {
  __shared__ unsigned short As[128 * 64];
  __shared__ unsigned short Bs[128 * 64];
  int tid = threadIdx.x;
  int wid = tid >> 6, lane = tid & 63;
  int m0 = blockIdx.y * 128, n0 = blockIdx.x * 128;
  int wr = wid >> 1, wc = wid & 1;
  f32x4 acc[4][4] = {};

  int srow_l = lane >> 3;         // row within 8-row segment
  int scol = (lane & 7) * 8;      // k element within 64
  int aReadBase = ((wr * 64 + (lane & 15)) * 128) + ((lane >> 4) * 16);
  int bReadBase = ((wc * 64 + (lane & 15)) * 128) + ((lane >> 4) * 16);

  const unsigned short* Ablk = A + (size_t)m0 * Kp;
  const unsigned short* Bblk = Bw + (size_t)n0 * Kp;

  for (int k0 = 0; k0 < Kp; k0 += 64) {
#pragma unroll
    for (int i = 0; i < 4; i++) {
      int s = wid * 4 + i;
      int row = s * 8 + srow_l;
      const unsigned short* ga = Ablk + (size_t)row * Kp + k0 + scol;
      const unsigned short* gb = Bblk + (size_t)row * Kp + k0 + scol;
      __builtin_amdgcn_global_load_lds((const __attribute__((address_space(1))) void*)ga,
                                       (__attribute__((address_space(3))) void*)(As + s * 512), 16, 0, 0);
      __builtin_amdgcn_global_load_lds((const __attribute__((address_space(1))) void*)gb,
                                       (__attribute__((address_space(3))) void*)(Bs + s * 512), 16, 0, 0);
    }
    __syncthreads();
#pragma unroll
    for (int kk = 0; kk < 2; kk++) {
      s16x8 af[4], bfr[4];
#pragma unroll
      for (int m = 0; m < 4; m++)
        af[m] = *(const s16x8*)((const char*)As + aReadBase + m * (16 * 128) + kk * 64);
#pragma unroll
      for (int n = 0; n < 4; n++)
        bfr[n] = *(const s16x8*)((const char*)Bs + bReadBase + n * (16 * 128) + kk * 64);
#pragma unroll
      for (int m = 0; m < 4; m++)
#pragma unroll
        for (int n = 0; n < 4; n++)
          acc[m][n] = __builtin_amdgcn_mfma_f32_16x16x32_bf16(af[m], bfr[n], acc[m][n], 0, 0, 0);
    }
    __syncthreads();
  }

  int rbase = m0 + wr * 64 + (lane >> 4) * 4;
  int cbase = n0 + wc * 64 + (lane & 15);
#pragma unroll
  for (int m = 0; m < 4; m++)
#pragma unroll
    for (int n = 0; n < 4; n++) {
      int col = cbase + n * 16;
      float bv = bias[col];
#pragma unroll
      for (int j = 0; j < 4; j++) {
        int row = rbase + m * 16 + j;
        float v = fmaxf(acc[m][n][j] + bv, 0.f);
        if (OUTBF16)
          ((unsigned short*)Cout)[(size_t)row * Nn + col] = f2bf(v);
        else
          ((float*)Cout)[(size_t)row * Nn + col] = v;
      }
    }
}

// fp32 fallback GEMM (used for fc3)
template <bool RELU>
__global__ __launch_bounds__(256) void gemm_bias(const float* __restrict__ A, const float* __restrict__ Bw,
                                                 const float* __restrict__ bias,
                                                 const float* __restrict__ scA, const float* __restrict__ shA,
                                                 float* __restrict__ C, int M, int Nn, int K) {
  const int BM = 64, BN = 64, BK = 16;
  __shared__ float As[BK][BM + 1];
  __shared__ float Bs[BK][BN + 1];
  int bm = blockIdx.y * BM, bn = blockIdx.x * BN;
  int tid = threadIdx.x;
  int tr = tid / 16, tc = tid % 16;
  float acc[4][4] = {};
  for (int k0 = 0; k0 < K; k0 += BK) {
    for (int i = tid; i < BM * BK; i += 256) {
      int m = i / BK, k = i % BK;
      float v = 0.f;
      if (k0 + k < K) {
        v = A[(size_t)(bm + m) * K + k0 + k];
        if (scA) v = fmaf(v, scA[k0 + k], shA[k0 + k]);
      }
      As[k][m] = v;
    }
    for (int i = tid; i < BN * BK; i += 256) {
      int n = i / BK, k = i % BK;
      float v = 0.f;
      if (k0 + k < K) v = Bw[(size_t)(bn + n) * K + k0 + k];
      Bs[k][n] = v;
    }
    __syncthreads();
#pragma unroll
    for (int k = 0; k < BK; k++) {
      float a4[4], b4[4];
#pragma unroll
      for (int xx = 0; xx < 4; xx++) a4[xx] = As[k][tr * 4 + xx];
#pragma unroll
      for (int yy = 0; yy < 4; yy++) b4[yy] = Bs[k][tc * 4 + yy];
#pragma unroll
      for (int xx = 0; xx < 4; xx++)
#pragma unroll
        for (int yy = 0; yy < 4; yy++) acc[xx][yy] = fmaf(a4[xx], b4[yy], acc[xx][yy]);
    }
    __syncthreads();
  }
  for (int xx = 0; xx < 4; xx++) {
    int m = bm + tr * 4 + xx;
    for (int yy = 0; yy < 4; yy++) {
      int n = bn + tc * 4 + yy;
      float v = acc[xx][yy] + bias[n];
      if (RELU) v = fmaxf(v, 0.f);
      C[(size_t)m * Nn + n] = v;
    }
  }
}

// per-column stats, fp32 input
__global__ __launch_bounds__(256) void colstats_kernel(const float* __restrict__ X, int M, int C,
                                                       float* __restrict__ sum, float* __restrict__ sumsq) {
  int cl = threadIdx.x & 63, rl = threadIdx.x >> 6;
  int c = blockIdx.x * 64 + cl;
  float s = 0.f, q = 0.f;
  int r0 = blockIdx.y * 256;
  int rend = min(r0 + 256, M);
  for (int r = r0 + rl; r < rend; r += 4) {
    float v = X[(size_t)r * C + c];
    s += v;
    q = fmaf(v, v, q);
  }
  __shared__ float ss[4][64];
  __shared__ float qq[4][64];
  ss[rl][cl] = s;
  qq[rl][cl] = q;
  __syncthreads();
  if (rl == 0) {
    s = ss[0][cl] + ss[1][cl] + ss[2][cl] + ss[3][cl];
    q = qq[0][cl] + qq[1][cl] + qq[2][cl] + qq[3][cl];
    atomicAdd(&sum[c], s);
    atomicAdd(&sumsq[c], q);
  }
}

// per-column stats, bf16 input
__global__ __launch_bounds__(256) void colstats_bf16_kernel(const unsigned short* __restrict__ X, int M, int C,
                                                            float* __restrict__ sum, float* __restrict__ sumsq) {
  int cl = threadIdx.x & 63, rl = threadIdx.x >> 6;
  int c = blockIdx.x * 64 + cl;
  float s = 0.f, q = 0.f;
  int r0 = blockIdx.y * 256;
  int rend = min(r0 + 256, M);
  for (int r = r0 + rl; r < rend; r += 4) {
    unsigned int u = X[(size_t)r * C + c];
    float v;
    u <<= 16;
    v = *(float*)&u;
    s += v;
    q = fmaf(v, v, q);
  }
  __shared__ float ss[4][64];
  __shared__ float qq[4][64];
  ss[rl][cl] = s;
  qq[rl][cl] = q;
  __syncthreads();
  if (rl == 0) {
    s = ss[0][cl] + ss[1][cl] + ss[2][cl] + ss[3][cl];
    q = qq[0][cl] + qq[1][cl] + qq[2][cl] + qq[3][cl];
    atomicAdd(&sum[c], s);
    atomicAdd(&sumsq[c], q);
  }
}

__global__ __launch_bounds__(256) void bn_coef_kernel(const float* __restrict__ sum, const float* __restrict__ sumsq,
                                                      const float* __restrict__ g, const float* __restrict__ be,
                                                      float* __restrict__ a, float* __restrict__ b, int C, float invM) {
  int c = blockIdx.x * blockDim.x + threadIdx.x;
  if (c >= C) return;
  float mu = sum[c] * invM;
  float var = sumsq[c] * invM - mu * mu;
  float s = g[c] * rsqrtf(var + 1e-5f);
  a[c] = s;
  b[c] = be[c] - mu * s;
}

__global__ __launch_bounds__(256) void head_kernel(const float* __restrict__ pooled, const float* __restrict__ cnt,
                                                   const float* __restrict__ m3, const float* __restrict__ a3,
                                                   const float* __restrict__ b3, const float* __restrict__ Wout,
                                                   const float* __restrict__ bout, float* __restrict__ out, int B) {
  int b = blockIdx.x * blockDim.x + threadIdx.x;
  if (b >= B) return;
  float inv = 1.f / fmaxf(cnt[b], 1.f);
  float acc = bout[0];
#pragma unroll
  for (int j = 0; j < 32; j++) acc = fmaf(pooled[(size_t)b * 32 + j] * inv, Wout[j], acc);
#pragma unroll
  for (int j = 0; j < 64; j++) acc = fmaf(fmaf(m3[(size_t)b * 64 + j], a3[j], b3[j]), Wout[32 + j], acc);
  out[b] = 1.f / (1.f + expf(-acc));
}

extern "C" void kernel_launch(void* const* d_in, const int* in_sizes, int n_in,
                              void* d_out, int out_size, void* d_ws, size_t ws_size,
                              hipStream_t stream) {
  const float* x = (const float*)d_in[0];
  const int* eidx = (const int*)d_in[1];
  const int* batch = (const int*)d_in[2];
  const float* xmord = (const float*)d_in[3];
  const float* Wl1 = (const float*)d_in[4];
  const float* bl1 = (const float*)d_in[5];
  const float* Wr1 = (const float*)d_in[6];
  const float* Wl2 = (const float*)d_in[7];
  const float* bl2 = (const float*)d_in[8];
  const float* Wr2 = (const float*)d_in[9];
  const float* Wl3 = (const float*)d_in[10];
  const float* bl3 = (const float*)d_in[11];
  const float* Wr3 = (const float*)d_in[12];
  const float* Wf1 = (const float*)d_in[13];
  const float* bf1 = (const float*)d_in[14];
  const float* g1 = (const float*)d_in[15];
  const float* be1 = (const float*)d_in[16];
  const float* Wf2 = (const float*)d_in[17];
  const float* bf2 = (const float*)d_in[18];
  const float* g2 = (const float*)d_in[19];
  const float* be2 = (const float*)d_in[20];
  const float* Wf3 = (const float*)d_in[21];
  const float* bf3 = (const float*)d_in[22];
  const float* g3 = (const float*)d_in[23];
  const float* be3 = (const float*)d_in[24];
  const float* Wout = (const float*)d_in[25];
  const float* bout = (const float*)d_in[26];
  float* out = (float*)d_out;

  const int N = in_sizes[2];
  const int E = in_sizes[1] / 2;
  const int B = in_sizes[3] / MORD;
  const int Kp1 = 896;  // 862 padded to multiple of 64
  const int* src = eidx;
  const int* dst = eidx + E;

  char* ws = (char*)d_ws;
  size_t off = 0;
  auto alloc = [&](size_t bytes) { size_t o = off; off += (bytes + 255) & ~(size_t)255; return o; };
  size_t oAGG = alloc((size_t)N * 32 * 4);
  size_t oA = alloc((size_t)N * 32 * 4);
  size_t oB = alloc((size_t)N * 32 * 4);
  size_t oDeg = alloc((size_t)N * 4);
  size_t oPool = alloc((size_t)B * 32 * 4);
  size_t oCnt = alloc((size_t)B * 4);
  size_t oStats = alloc(4096 * 4);
  (void)ws_size;

  float* AGG = (float*)(ws + oAGG);
  float* OA = (float*)(ws + oA);
  float* OB = (float*)(ws + oB);
  int* deg = (int*)(ws + oDeg);
  float* pooled = (float*)(ws + oPool);
  float* cnt = (float*)(ws + oCnt);
  float* st = (float*)(ws + oStats);
  float *s1 = st, *q1 = st + 512, *a1 = st + 1024, *h1 = st + 1536;
  float *s2 = st + 2048, *q2 = st + 2176, *a2 = st + 2304, *h2 = st + 2432;
  float *s3 = st + 2560, *q3 = st + 2624, *a3 = st + 2688, *h3 = st + 2752;

  // bf16 MLP buffers carved out of freed GNN regions (stream-serialized lifetimes):
  // OB region free after transform3: Abf [16384,896] bf16 (28.7MB) + Bbf1 [512,896] bf16 + W2p + b2p
  unsigned short* Abf = (unsigned short*)(ws + oB);
  unsigned short* Bbf1 = (unsigned short*)(ws + oB + 29360128);            // 16384*896*2
  unsigned short* W2p = (unsigned short*)(ws + oB + 29360128 + 917504);    // + 512*896*2
  float* b2p = (float*)(ws + oB + 29360128 + 917504 + 131072);             // + 128*512*2
  // AGG region free after transform3: m1 bf16 [16384,512] (16.8MB), m2 f32 [16384,128], m3 f32 [16384,64]
  unsigned short* m1 = (unsigned short*)(ws + oAGG);
  float* m2 = (float*)(ws + oAGG + 16777216);
  float* m3 = (float*)(ws + oAGG + 25165824);

  hipMemsetAsync(deg, 0, (size_t)N * 4, stream);
  hipMemsetAsync(AGG, 0, (size_t)N * 8 * 4, stream);
  hipMemsetAsync(pooled, 0, (size_t)B * 32 * 4, stream);
  hipMemsetAsync(cnt, 0, (size_t)B * 4, stream);
  hipMemsetAsync(st, 0, 4096 * 4, stream);

  deg_kernel<<<(E + 255) / 256, 256, 0, stream>>>(dst, deg, E);

  // layer 1 (Cin=8)
  scatter_kernel<8><<<(int)(((long long)E * 8 + 255) / 256), 256, 0, stream>>>(x, src, dst, AGG, E);
  transform_kernel<8, true><<<N / 8, 256, 0, stream>>>(AGG, x, deg, Wl1, bl1, Wr1, OA, N);

  // layer 2 (Cin=32)
  hipMemsetAsync(AGG, 0, (size_t)N * 32 * 4, stream);
  scatter_kernel<32><<<(int)(((long long)E * 32 + 255) / 256), 256, 0, stream>>>(OA, src, dst, AGG, E);
  transform_kernel<32, true><<<N / 8, 256, 0, stream>>>(AGG, OA, deg, Wl2, bl2, Wr2, OB, N);

  // layer 3 (Cin=32)
  hipMemsetAsync(AGG, 0, (size_t)N * 32 * 4, stream);
  scatter_kernel<32><<<(int)(((long long)E * 32 + 255) / 256), 256, 0, stream>>>(OB, src, dst, AGG, E);
  transform_kernel<32, false><<<N / 8, 256, 0, stream>>>(AGG, OB, deg, Wl3, bl3, Wr3, OA, N);

  pool_kernel<<<(int)(((long long)N * 32 + 255) / 256), 256, 0, stream>>>(OA, batch, pooled, cnt, N);

  // ---- MLP head (bf16 MFMA for fc1/fc2) ----
  cvt_bf16_pad<<<(B * (Kp1 / 4) + 255) / 256, 256, 0, stream>>>(xmord, Abf, B, MORD, Kp1);
  cvt_bf16_pad<<<(512 * (Kp1 / 4) + 255) / 256, 256, 0, stream>>>(Wf1, Bbf1, 512, MORD, Kp1);

  gemm_mfma<1><<<dim3(512 / 128, B / 128), 256, 0, stream>>>(Abf, Bbf1, bf1, m1, B, 512, Kp1);
  colstats_bf16_kernel<<<dim3(512 / 64, B / 256), 256, 0, stream>>>(m1, B, 512, s1, q1);
  bn_coef_kernel<<<2, 256, 0, stream>>>(s1, q1, g1, be1, a1, h1, 512, 1.f / B);

  prepW2_kernel<<<32, 256, 0, stream>>>(Wf2, bf2, a1, h1, W2p, b2p, 128, 512);
  gemm_mfma<0><<<dim3(128 / 128, B / 128), 256, 0, stream>>>(m1, W2p, b2p, m2, B, 128, 512);
  colstats_kernel<<<dim3(128 / 64, B / 256), 256, 0, stream>>>(m2, B, 128, s2, q2);
  bn_coef_kernel<<<1, 256, 0, stream>>>(s2, q2, g2, be2, a2, h2, 128, 1.f / B);

  gemm_bias<true><<<dim3(64 / 64, B / 64), 256, 0, stream>>>(m2, Wf3, bf3, a2, h2, m3, B, 64, 128);
  colstats_kernel<<<dim3(1, B / 256), 256, 0, stream>>>(m3, B, 64, s3, q3);
  bn_coef_kernel<<<1, 256, 0, stream>>>(s3, q3, g3, be3, a3, h3, 64, 1.f / B);

  head_kernel<<<(B + 255) / 256, 256, 0, stream>>>(pooled, cnt, m3, a3, h3, Wout, bout, out, B);
}

// Round 3
// 917.409 us; speedup vs baseline: 1.9393x; 1.4882x over previous
//
#include <hip/hip_runtime.h>
#include <hip/hip_bf16.h>
#include <math.h>

#define MORD 862

typedef short s16x8 __attribute__((ext_vector_type(8)));
typedef float f32x4 __attribute__((ext_vector_type(4)));

static __device__ __forceinline__ unsigned short f2bf(float v) {
  __hip_bfloat16 h = __float2bfloat16(v);
  return *(unsigned short*)&h;
}

__global__ __launch_bounds__(256) void deg_kernel(const int* __restrict__ dst, int* __restrict__ deg, int E) {
  int e = blockIdx.x * blockDim.x + threadIdx.x;
  if (e < E) atomicAdd(&deg[dst[e]], 1);
}

template <int C>
__global__ __launch_bounds__(256) void scatter_kernel(const float* __restrict__ x, const int* __restrict__ src,
                                                      const int* __restrict__ dst, float* __restrict__ h, int E) {
  long long tid = (long long)blockIdx.x * blockDim.x + threadIdx.x;
  if (tid >= (long long)E * C) return;
  int e = (int)(tid / C);
  int c = (int)(tid % C);
  atomicAdd(&h[(long long)dst[e] * C + c], x[(long long)src[e] * C + c]);
}

// LDS-staged weights, transposed [d][i][o]; grid-stride over 16-node tiles; 512 threads.
template <int CIN, bool RELU>
__global__ __launch_bounds__(512) void transform_lds(const float* __restrict__ hagg, const float* __restrict__ xin,
                                                     const int* __restrict__ deg,
                                                     const float* __restrict__ Wl, const float* __restrict__ bl,
                                                     const float* __restrict__ Wr,
                                                     float* __restrict__ out, int N) {
  __shared__ float swl[11 * CIN * 32];
  __shared__ float swr[11 * CIN * 32];
  __shared__ float sbl[11 * 32];
  __shared__ float sh[16 * CIN];
  __shared__ float sx[16 * CIN];

  for (int idx = threadIdx.x; idx < 11 * CIN * 32; idx += 512) {
    int d = idx / (CIN * 32);
    int i = (idx >> 5) % CIN;
    int o = idx & 31;
    swl[idx] = Wl[((size_t)d * 32 + o) * CIN + i];
    swr[idx] = Wr[((size_t)d * 32 + o) * CIN + i];
  }
  for (int idx = threadIdx.x; idx < 11 * 32; idx += 512) sbl[idx] = bl[idx];
  __syncthreads();

  int o = threadIdx.x & 31, ns = threadIdx.x >> 5;  // ns in 0..15
  for (long long n0 = (long long)blockIdx.x * 16; n0 < N; n0 += (long long)gridDim.x * 16) {
    long long remain = (long long)N - n0;
    int cnt = remain < 16 ? (int)remain : 16;
    __syncthreads();
    for (int idx = threadIdx.x; idx < cnt * CIN; idx += 512) {
      sh[idx] = hagg[n0 * CIN + idx];
      sx[idx] = xin[n0 * CIN + idx];
    }
    __syncthreads();
    long long n = n0 + ns;
    if (ns < cnt) {
      int d = min(deg[n], 10);
      int wb = d * CIN * 32 + o;
      float acc = sbl[d * 32 + o];
#pragma unroll
      for (int i = 0; i < CIN; i++)
        acc = fmaf(swl[wb + i * 32], sh[ns * CIN + i], fmaf(swr[wb + i * 32], sx[ns * CIN + i], acc));
      if (RELU) acc = fmaxf(acc, 0.f);
      out[n * 32 + o] = acc;
    }
  }
}

__global__ __launch_bounds__(256) void pool_kernel(const float* __restrict__ h, const int* __restrict__ batch,
                                                   float* __restrict__ pooled, float* __restrict__ cnt, int N) {
  long long tid = (long long)blockIdx.x * blockDim.x + threadIdx.x;
  if (tid >= (long long)N * 32) return;
  int n = (int)(tid >> 5), c = (int)(tid & 31);
  int b = batch[n];
  atomicAdd(&pooled[(long long)b * 32 + c], h[tid]);
  if (c == 0) atomicAdd(&cnt[b], 1.f);
}

// fp32 -> bf16 with K padding to Kp (zeros in pad)
__global__ __launch_bounds__(256) void cvt_bf16_pad(const float* __restrict__ src, unsigned short* __restrict__ dst,
                                                    int rows, int K, int Kp) {
  int t = blockIdx.x * blockDim.x + threadIdx.x;
  int q = Kp / 4;
  if (t >= rows * q) return;
  int r = t / q, c4 = (t % q) * 4;
#pragma unroll
  for (int j = 0; j < 4; j++) {
    int k = c4 + j;
    float v = (k < K) ? src[(size_t)r * K + k] : 0.f;
    dst[(size_t)r * Kp + k] = f2bf(v);
  }
}

// W2'[n][k] = bf16(W2[n][k]*a1[k]); b2'[n] = b2[n] + sum_k h1[k]*W2[n][k].  one wave per n.
__global__ __launch_bounds__(256) void prepW2_kernel(const float* __restrict__ W2, const float* __restrict__ b2,
                                                     const float* __restrict__ a1, const float* __restrict__ h1,
                                                     unsigned short* __restrict__ W2p, float* __restrict__ b2p,
                                                     int Nn, int K) {
  int wid = threadIdx.x >> 6, lane = threadIdx.x & 63;
  int n = blockIdx.x * 4 + wid;
  if (n >= Nn) return;
  float part = 0.f;
  for (int k = lane; k < K; k += 64) {
    float w = W2[(size_t)n * K + k];
    W2p[(size_t)n * K + k] = f2bf(w * a1[k]);
    part = fmaf(w, h1[k], part);
  }
#pragma unroll
  for (int off = 32; off > 0; off >>= 1) part += __shfl_down(part, off, 64);
  if (lane == 0) b2p[n] = b2[n] + part;
}

// bf16 MFMA GEMM: C[M,Nn] = relu(A[M,Kp] @ Bw[Nn,Kp]^T + bias). 128x128 tile, BK=64.
template <int OUTBF16>
__global__ __launch_bounds__(256) void gemm_mfma(const unsigned short* __restrict__ A,
                                                 const unsigned short* __restrict__ Bw,
                                                 const float* __restrict__ bias,
                                                 void* __restrict__ Cout, int M, int Nn, int Kp) {
  __shared__ unsigned short As[128 * 64];
  __shared__ unsigned short Bs[128 * 64];
  int tid = threadIdx.x;
  int wid = tid >> 6, lane = tid & 63;
  int m0 = blockIdx.y * 128, n0 = blockIdx.x * 128;
  int wr = wid >> 1, wc = wid & 1;
  f32x4 acc[4][4] = {};

  int srow_l = lane >> 3;
  int scol = (lane & 7) * 8;
  int aReadBase = ((wr * 64 + (lane & 15)) * 128) + ((lane >> 4) * 16);
  int bReadBase = ((wc * 64 + (lane & 15)) * 128) + ((lane >> 4) * 16);

  const unsigned short* Ablk = A + (size_t)m0 * Kp;
  const unsigned short* Bblk = Bw + (size_t)n0 * Kp;

  for (int k0 = 0; k0 < Kp; k0 += 64) {
#pragma unroll
    for (int i = 0; i < 4; i++) {
      int s = wid * 4 + i;
      int row = s * 8 + srow_l;
      const unsigned short* ga = Ablk + (size_t)row * Kp + k0 + scol;
      const unsigned short* gb = Bblk + (size_t)row * Kp + k0 + scol;
      __builtin_amdgcn_global_load_lds((const __attribute__((address_space(1))) void*)ga,
                                       (__attribute__((address_space(3))) void*)(As + s * 512), 16, 0, 0);
      __builtin_amdgcn_global_load_lds((const __attribute__((address_space(1))) void*)gb,
                                       (__attribute__((address_space(3))) void*)(Bs + s * 512), 16, 0, 0);
    }
    __syncthreads();
#pragma unroll
    for (int kk = 0; kk < 2; kk++) {
      s16x8 af[4], bfr[4];
#pragma unroll
      for (int m = 0; m < 4; m++)
        af[m] = *(const s16x8*)((const char*)As + aReadBase + m * (16 * 128) + kk * 64);
#pragma unroll
      for (int n = 0; n < 4; n++)
        bfr[n] = *(const s16x8*)((const char*)Bs + bReadBase + n * (16 * 128) + kk * 64);
#pragma unroll
      for (int m = 0; m < 4; m++)
#pragma unroll
        for (int n = 0; n < 4; n++)
          acc[m][n] = __builtin_amdgcn_mfma_f32_16x16x32_bf16(af[m], bfr[n], acc[m][n], 0, 0, 0);
    }
    __syncthreads();
  }

  int rbase = m0 + wr * 64 + (lane >> 4) * 4;
  int cbase = n0 + wc * 64 + (lane & 15);
#pragma unroll
  for (int m = 0; m < 4; m++)
#pragma unroll
    for (int n = 0; n < 4; n++) {
      int col = cbase + n * 16;
      float bv = bias[col];
#pragma unroll
      for (int j = 0; j < 4; j++) {
        int row = rbase + m * 16 + j;
        float v = fmaxf(acc[m][n][j] + bv, 0.f);
        if (OUTBF16)
          ((unsigned short*)Cout)[(size_t)row * Nn + col] = f2bf(v);
        else
          ((float*)Cout)[(size_t)row * Nn + col] = v;
      }
    }
}

// fp32 fallback GEMM (used for fc3)
template <bool RELU>
__global__ __launch_bounds__(256) void gemm_bias(const float* __restrict__ A, const float* __restrict__ Bw,
                                                 const float* __restrict__ bias,
                                                 const float* __restrict__ scA, const float* __restrict__ shA,
                                                 float* __restrict__ C, int M, int Nn, int K) {
  const int BM = 64, BN = 64, BK = 16;
  __shared__ float As[BK][BM + 1];
  __shared__ float Bs[BK][BN + 1];
  int bm = blockIdx.y * BM, bn = blockIdx.x * BN;
  int tid = threadIdx.x;
  int tr = tid / 16, tc = tid % 16;
  float acc[4][4] = {};
  for (int k0 = 0; k0 < K; k0 += BK) {
    for (int i = tid; i < BM * BK; i += 256) {
      int m = i / BK, k = i % BK;
      float v = 0.f;
      if (k0 + k < K) {
        v = A[(size_t)(bm + m) * K + k0 + k];
        if (scA) v = fmaf(v, scA[k0 + k], shA[k0 + k]);
      }
      As[k][m] = v;
    }
    for (int i = tid; i < BN * BK; i += 256) {
      int n = i / BK, k = i % BK;
      float v = 0.f;
      if (k0 + k < K) v = Bw[(size_t)(bn + n) * K + k0 + k];
      Bs[k][n] = v;
    }
    __syncthreads();
#pragma unroll
    for (int k = 0; k < BK; k++) {
      float a4[4], b4[4];
#pragma unroll
      for (int xx = 0; xx < 4; xx++) a4[xx] = As[k][tr * 4 + xx];
#pragma unroll
      for (int yy = 0; yy < 4; yy++) b4[yy] = Bs[k][tc * 4 + yy];
#pragma unroll
      for (int xx = 0; xx < 4; xx++)
#pragma unroll
        for (int yy = 0; yy < 4; yy++) acc[xx][yy] = fmaf(a4[xx], b4[yy], acc[xx][yy]);
    }
    __syncthreads();
  }
  for (int xx = 0; xx < 4; xx++) {
    int m = bm + tr * 4 + xx;
    for (int yy = 0; yy < 4; yy++) {
      int n = bn + tc * 4 + yy;
      float v = acc[xx][yy] + bias[n];
      if (RELU) v = fmaxf(v, 0.f);
      C[(size_t)m * Nn + n] = v;
    }
  }
}

// per-column stats, fp32 input
__global__ __launch_bounds__(256) void colstats_kernel(const float* __restrict__ X, int M, int C,
                                                       float* __restrict__ sum, float* __restrict__ sumsq) {
  int cl = threadIdx.x & 63, rl = threadIdx.x >> 6;
  int c = blockIdx.x * 64 + cl;
  float s = 0.f, q = 0.f;
  int r0 = blockIdx.y * 256;
  int rend = min(r0 + 256, M);
  for (int r = r0 + rl; r < rend; r += 4) {
    float v = X[(size_t)r * C + c];
    s += v;
    q = fmaf(v, v, q);
  }
  __shared__ float ss[4][64];
  __shared__ float qq[4][64];
  ss[rl][cl] = s;
  qq[rl][cl] = q;
  __syncthreads();
  if (rl == 0) {
    s = ss[0][cl] + ss[1][cl] + ss[2][cl] + ss[3][cl];
    q = qq[0][cl] + qq[1][cl] + qq[2][cl] + qq[3][cl];
    atomicAdd(&sum[c], s);
    atomicAdd(&sumsq[c], q);
  }
}

// per-column stats, bf16 input
__global__ __launch_bounds__(256) void colstats_bf16_kernel(const unsigned short* __restrict__ X, int M, int C,
                                                            float* __restrict__ sum, float* __restrict__ sumsq) {
  int cl = threadIdx.x & 63, rl = threadIdx.x >> 6;
  int c = blockIdx.x * 64 + cl;
  float s = 0.f, q = 0.f;
  int r0 = blockIdx.y * 256;
  int rend = min(r0 + 256, M);
  for (int r = r0 + rl; r < rend; r += 4) {
    unsigned int u = X[(size_t)r * C + c];
    float v;
    u <<= 16;
    v = *(float*)&u;
    s += v;
    q = fmaf(v, v, q);
  }
  __shared__ float ss[4][64];
  __shared__ float qq[4][64];
  ss[rl][cl] = s;
  qq[rl][cl] = q;
  __syncthreads();
  if (rl == 0) {
    s = ss[0][cl] + ss[1][cl] + ss[2][cl] + ss[3][cl];
    q = qq[0][cl] + qq[1][cl] + qq[2][cl] + qq[3][cl];
    atomicAdd(&sum[c], s);
    atomicAdd(&sumsq[c], q);
  }
}

__global__ __launch_bounds__(256) void bn_coef_kernel(const float* __restrict__ sum, const float* __restrict__ sumsq,
                                                      const float* __restrict__ g, const float* __restrict__ be,
                                                      float* __restrict__ a, float* __restrict__ b, int C, float invM) {
  int c = blockIdx.x * blockDim.x + threadIdx.x;
  if (c >= C) return;
  float mu = sum[c] * invM;
  float var = sumsq[c] * invM - mu * mu;
  float s = g[c] * rsqrtf(var + 1e-5f);
  a[c] = s;
  b[c] = be[c] - mu * s;
}

__global__ __launch_bounds__(256) void head_kernel(const float* __restrict__ pooled, const float* __restrict__ cnt,
                                                   const float* __restrict__ m3, const float* __restrict__ a3,
                                                   const float* __restrict__ b3, const float* __restrict__ Wout,
                                                   const float* __restrict__ bout, float* __restrict__ out, int B) {
  int b = blockIdx.x * blockDim.x + threadIdx.x;
  if (b >= B) return;
  float inv = 1.f / fmaxf(cnt[b], 1.f);
  float acc = bout[0];
#pragma unroll
  for (int j = 0; j < 32; j++) acc = fmaf(pooled[(size_t)b * 32 + j] * inv, Wout[j], acc);
#pragma unroll
  for (int j = 0; j < 64; j++) acc = fmaf(fmaf(m3[(size_t)b * 64 + j], a3[j], b3[j]), Wout[32 + j], acc);
  out[b] = 1.f / (1.f + expf(-acc));
}

extern "C" void kernel_launch(void* const* d_in, const int* in_sizes, int n_in,
                              void* d_out, int out_size, void* d_ws, size_t ws_size,
                              hipStream_t stream) {
  const float* x = (const float*)d_in[0];
  const int* eidx = (const int*)d_in[1];
  const int* batch = (const int*)d_in[2];
  const float* xmord = (const float*)d_in[3];
  const float* Wl1 = (const float*)d_in[4];
  const float* bl1 = (const float*)d_in[5];
  const float* Wr1 = (const float*)d_in[6];
  const float* Wl2 = (const float*)d_in[7];
  const float* bl2 = (const float*)d_in[8];
  const float* Wr2 = (const float*)d_in[9];
  const float* Wl3 = (const float*)d_in[10];
  const float* bl3 = (const float*)d_in[11];
  const float* Wr3 = (const float*)d_in[12];
  const float* Wf1 = (const float*)d_in[13];
  const float* bf1 = (const float*)d_in[14];
  const float* g1 = (const float*)d_in[15];
  const float* be1 = (const float*)d_in[16];
  const float* Wf2 = (const float*)d_in[17];
  const float* bf2 = (const float*)d_in[18];
  const float* g2 = (const float*)d_in[19];
  const float* be2 = (const float*)d_in[20];
  const float* Wf3 = (const float*)d_in[21];
  const float* bf3 = (const float*)d_in[22];
  const float* g3 = (const float*)d_in[23];
  const float* be3 = (const float*)d_in[24];
  const float* Wout = (const float*)d_in[25];
  const float* bout = (const float*)d_in[26];
  float* out = (float*)d_out;

  const int N = in_sizes[2];
  const int E = in_sizes[1] / 2;
  const int B = in_sizes[3] / MORD;
  const int Kp1 = 896;
  const int* src = eidx;
  const int* dst = eidx + E;

  char* ws = (char*)d_ws;
  size_t off = 0;
  auto alloc = [&](size_t bytes) { size_t o = off; off += (bytes + 255) & ~(size_t)255; return o; };
  size_t oAGG = alloc((size_t)N * 32 * 4);
  size_t oA = alloc((size_t)N * 32 * 4);
  size_t oB = alloc((size_t)N * 32 * 4);
  size_t oDeg = alloc((size_t)N * 4);
  size_t oPool = alloc((size_t)B * 32 * 4);
  size_t oCnt = alloc((size_t)B * 4);
  size_t oStats = alloc(4096 * 4);
  (void)ws_size;

  float* AGG = (float*)(ws + oAGG);
  float* OA = (float*)(ws + oA);
  float* OB = (float*)(ws + oB);
  int* deg = (int*)(ws + oDeg);
  float* pooled = (float*)(ws + oPool);
  float* cnt = (float*)(ws + oCnt);
  float* st = (float*)(ws + oStats);
  float *s1 = st, *q1 = st + 512, *a1 = st + 1024, *h1 = st + 1536;
  float *s2 = st + 2048, *q2 = st + 2176, *a2 = st + 2304, *h2 = st + 2432;
  float *s3 = st + 2560, *q3 = st + 2624, *a3 = st + 2688, *h3 = st + 2752;

  unsigned short* Abf = (unsigned short*)(ws + oB);
  unsigned short* Bbf1 = (unsigned short*)(ws + oB + 29360128);
  unsigned short* W2p = (unsigned short*)(ws + oB + 29360128 + 917504);
  float* b2p = (float*)(ws + oB + 29360128 + 917504 + 131072);
  unsigned short* m1 = (unsigned short*)(ws + oAGG);
  float* m2 = (float*)(ws + oAGG + 16777216);
  float* m3 = (float*)(ws + oAGG + 25165824);

  hipMemsetAsync(deg, 0, (size_t)N * 4, stream);
  hipMemsetAsync(AGG, 0, (size_t)N * 8 * 4, stream);
  hipMemsetAsync(pooled, 0, (size_t)B * 32 * 4, stream);
  hipMemsetAsync(cnt, 0, (size_t)B * 4, stream);
  hipMemsetAsync(st, 0, 4096 * 4, stream);

  deg_kernel<<<(E + 255) / 256, 256, 0, stream>>>(dst, deg, E);

  // layer 1 (Cin=8)
  scatter_kernel<8><<<(int)(((long long)E * 8 + 255) / 256), 256, 0, stream>>>(x, src, dst, AGG, E);
  transform_lds<8, true><<<1024, 512, 0, stream>>>(AGG, x, deg, Wl1, bl1, Wr1, OA, N);

  // layer 2 (Cin=32)
  hipMemsetAsync(AGG, 0, (size_t)N * 32 * 4, stream);
  scatter_kernel<32><<<(int)(((long long)E * 32 + 255) / 256), 256, 0, stream>>>(OA, src, dst, AGG, E);
  transform_lds<32, true><<<256, 512, 0, stream>>>(AGG, OA, deg, Wl2, bl2, Wr2, OB, N);

  // layer 3 (Cin=32)
  hipMemsetAsync(AGG, 0, (size_t)N * 32 * 4, stream);
  scatter_kernel<32><<<(int)(((long long)E * 32 + 255) / 256), 256, 0, stream>>>(OB, src, dst, AGG, E);
  transform_lds<32, false><<<256, 512, 0, stream>>>(AGG, OB, deg, Wl3, bl3, Wr3, OA, N);

  pool_kernel<<<(int)(((long long)N * 32 + 255) / 256), 256, 0, stream>>>(OA, batch, pooled, cnt, N);

  // ---- MLP head (bf16 MFMA for fc1/fc2) ----
  cvt_bf16_pad<<<(B * (Kp1 / 4) + 255) / 256, 256, 0, stream>>>(xmord, Abf, B, MORD, Kp1);
  cvt_bf16_pad<<<(512 * (Kp1 / 4) + 255) / 256, 256, 0, stream>>>(Wf1, Bbf1, 512, MORD, Kp1);

  gemm_mfma<1><<<dim3(512 / 128, B / 128), 256, 0, stream>>>(Abf, Bbf1, bf1, m1, B, 512, Kp1);
  colstats_bf16_kernel<<<dim3(512 / 64, B / 256), 256, 0, stream>>>(m1, B, 512, s1, q1);
  bn_coef_kernel<<<2, 256, 0, stream>>>(s1, q1, g1, be1, a1, h1, 512, 1.f / B);

  prepW2_kernel<<<32, 256, 0, stream>>>(Wf2, bf2, a1, h1, W2p, b2p, 128, 512);
  gemm_mfma<0><<<dim3(128 / 128, B / 128), 256, 0, stream>>>(m1, W2p, b2p, m2, B, 128, 512);
  colstats_kernel<<<dim3(128 / 64, B / 256), 256, 0, stream>>>(m2, B, 128, s2, q2);
  bn_coef_kernel<<<1, 256, 0, stream>>>(s2, q2, g2, be2, a2, h2, 128, 1.f / B);

  gemm_bias<true><<<dim3(64 / 64, B / 64), 256, 0, stream>>>(m2, Wf3, bf3, a2, h2, m3, B, 64, 128);
  colstats_kernel<<<dim3(1, B / 256), 256, 0, stream>>>(m3, B, 64, s3, q3);
  bn_coef_kernel<<<1, 256, 0, stream>>>(s3, q3, g3, be3, a3, h3, 64, 1.f / B);

  head_kernel<<<(B + 255) / 256, 256, 0, stream>>>(pooled, cnt, m3, a3, h3, Wout, bout, out, B);
}